// Round 8
// baseline (1001.568 us; speedup 1.0000x reference)
//
#include <hip/hip_runtime.h>
#include <cmath>

// Forbid FMA contraction: the reference check is a float32 numpy replay with
// individually-rounded ops. We opt into FMA explicitly (fmaf) only where
// BLAS sgemm itself uses an FMA chain.
#pragma clang fp contract(off)

#define NLV 16
#define TSZ (1u << 19)
#define TMASK (TSZ - 1u)
#define PR1 2654435761u
#define PR2 805459861u

typedef float v2f __attribute__((ext_vector_type(2)));
typedef float v4f __attribute__((ext_vector_type(4)));

struct ResT { float r[NLV]; };

// ---------- shared helpers (bit-exact fp32, matches np reference) ----------
__device__ __forceinline__ void aabb_norm_v(
    float a0, float a1, float a2, float a3, float a4, float a5,
    float posx, float posy, float posz,
    float& s0, float& s1, float& s2,
    float& pnx, float& pny, float& pnz, bool& sel)
{
    s0 = fmaxf(a3 - a0, 1e-6f);
    s1 = fmaxf(a4 - a1, 1e-6f);
    s2 = fmaxf(a5 - a2, 1e-6f);
    float nx = (posx - a0) / s0;
    float ny = (posy - a1) / s1;
    float nz = (posz - a2) / s2;
    sel = (nx >= 0.f) && (nx <= 1.f) && (ny >= 0.f) && (ny <= 1.f)
       && (nz >= 0.f) && (nz <= 1.f);
    pnx = fminf(fmaxf(nx, 0.f), 1.f);
    pny = fminf(fmaxf(ny, 0.f), 1.f);
    pnz = fminf(fmaxf(nz, 0.f), 1.f);
}

__device__ __forceinline__ void aabb_norm(
    const float* __restrict__ g_aabb, float posx, float posy, float posz,
    float& s0, float& s1, float& s2,
    float& pnx, float& pny, float& pnz, bool& sel)
{
    aabb_norm_v(g_aabb[0], g_aabb[1], g_aabb[2], g_aabb[3], g_aabb[4], g_aabb[5],
                posx, posy, posz, s0, s1, s2, pnx, pny, pnz, sel);
}

// =====================================================================
// PASS A: one (point, level) per thread. ROUND-3/4 CONFIG EXACTLY
// (measured 167-172 us, FETCH 95 MB): two time phases; phase 0 runs
// levels 0..7 with level l pinned to XCD l (b%8 round-robin), phase 1
// runs levels 8..15. Each XCD holds ONE 4 MB slice at a time ->
// L2-resident. Floor = L2 random-request throughput (~10 req/cyc/XCD),
// mapping-invariant request count.
// NT STORES ARE LOAD-BEARING (r7 proved it): plain stores stream 16 MB
// of dirty ws per XCD through the 4 MB L2 holding the pinned slice ->
// pass A regressed to ~260 us. NT keeps the slice resident; the cost
// (pass B reads ws from HBM, ~900cyc) is handled by pass B's batched
// load ILP.
// ws layout packed for pass B:
//   f2[l*N+n]  = (f0,f1)           (v2f plane)
//   p4[l*N+n]  = (xa,xb,ya,yb)     (v4f plane)
//   p2[l*N+n]  = (za,zb)           (v2f plane)
// =====================================================================
__global__ __launch_bounds__(256) void level_gather(
    const float* __restrict__ g_pos,
    const float* __restrict__ g_tab,
    const float* __restrict__ g_aabb,
    float* __restrict__ ws,
    int N, int chunks, ResT rt)
{
    int b = blockIdx.x;
    int half = (b >= 8 * chunks) ? 1 : 0;
    int bb = b - half * (8 * chunks);
    int lvl = (bb & 7) + (half << 3);
    int n = (bb >> 3) * 256 + threadIdx.x;
    if (n >= N) return;

    float posx = g_pos[3*n+0], posy = g_pos[3*n+1], posz = g_pos[3*n+2];
    float s0, s1, s2, pnx, pny, pnz; bool sel;
    aabb_norm(g_aabb, posx, posy, posz, s0, s1, s2, pnx, pny, pnz, sel);

    float res = rt.r[lvl];                       // wave-uniform scalar
    const float2* tl = (const float2*)g_tab + (size_t)lvl * TSZ;

    float fx = pnx * res, fy = pny * res, fz = pnz * res;
    float x0 = floorf(fx), y0 = floorf(fy), z0 = floorf(fz);
    float wx = fx - x0, wy = fy - y0, wz = fz - z0;
    float omx = 1.f - wx, omy = 1.f - wy, omz = 1.f - wz;
    unsigned ux = (unsigned)x0, uy = (unsigned)y0, uz = (unsigned)z0;
    unsigned hx0 = ux,        hx1 = ux + 1u;
    unsigned hy0 = uy * PR1,  hy1 = (uy + 1u) * PR1;
    unsigned hz0 = uz * PR2,  hz1 = (uz + 1u) * PR2;
    float f0 = 0.f, f1 = 0.f;
    float lxa = 0.f, lxb = 0.f, lya = 0.f, lyb = 0.f, lza = 0.f, lzb = 0.f;
#pragma unroll
    for (int c = 0; c < 8; ++c) {
        unsigned hh = ((c & 4) ? hx1 : hx0) ^ ((c & 2) ? hy1 : hy0) ^ ((c & 1) ? hz1 : hz0);
        float2 fv = tl[hh & TMASK];
        float wxv = (c & 4) ? wx : omx;
        float wyv = (c & 2) ? wy : omy;
        float wzv = (c & 1) ? wz : omz;
        // forward: wc = (x*y)*z, each op rounded; f += fv*wc seq c=0..7
        float wgt = wxv * wyv;
        wgt = wgt * wzv;
        float t0 = fv.x * wgt;
        float t1 = fv.y * wgt;
        f0 = f0 + t0;
        f1 = f1 + t1;
        // gradient partials (sign flip by corner bit is exact)
        float pyz = wyv * wzv;
        float pxz = wxv * wzv;
        float pxy = wxv * wyv;
        float spx = (c & 4) ? pyz : -pyz;
        float spy = (c & 2) ? pxz : -pxz;
        float spz = (c & 1) ? pxy : -pxy;
        lxa = lxa + fv.x * spx;  lxb = lxb + fv.y * spx;
        lya = lya + fv.x * spy;  lyb = lyb + fv.y * spy;
        lza = lza + fv.x * spz;  lzb = lzb + fv.y * spz;
    }

    size_t LN = (size_t)NLV * N;
    size_t idx = (size_t)lvl * N + n;
    v2f* f2 = (v2f*)ws;                  // 2*LN floats
    v4f* p4 = (v4f*)(ws + 2*LN);         // 4*LN floats
    v2f* p2 = (v2f*)(ws + 6*LN);         // 2*LN floats
    v2f ff = {f0, f1};
    v4f pa = {lxa, lxb, lya, lyb};
    v2f pz = {lza, lzb};
    __builtin_nontemporal_store(ff, f2 + idx);
    __builtin_nontemporal_store(pa, p4 + idx);
    __builtin_nontemporal_store(pz, p2 + idx);
}

// =====================================================================
// PASS B: TWO THREADS PER POINT (pair-split, modeled on the validated
// ngp_fused exchange pattern). r5/r6/r7 proved 1-thread-per-point can't
// pipeline its 48 loads without blowing the register file (256 VGPR +
// spills, or cap-forced spills). Pair-split gives the ILP through
// thread parallelism instead:
//  - thread p loads its 8 f2 pairs in ONE batch (16 VGPR in flight);
//    __shfl_xor(.,1) exchange reconstructs all 16 levels in EXACT
//    reference order for the z1 chain (ngp_fused-identical rounding).
//  - 8 p4 + 8 p2 partials issued in ONE batch (48 VGPR) right before
//    the 1024-fmaf sh loop, which covers their HBM latency.
//  - weights in LDS -> in-loop reads are ds_read; vmcnt queue holds
//    only ws loads.
//  - grad computed per-half then shfl-combined (ngp_fused-identical,
//    validated rounding). p==0 stages the full 39-float row in LDS;
//    block stores 128 points coalesced as float4s.
// No launch_bounds cap (r7 lesson).
// =====================================================================
__global__ __launch_bounds__(256) void mlp_bwd(
    const float* __restrict__ g_pos,
    const float* __restrict__ g_rx,
    const float* __restrict__ g_W1,
    const float* __restrict__ g_W2,
    const float* __restrict__ g_aabb,
    const int*   __restrict__ g_deg,
    const float* __restrict__ ws,
    float* __restrict__ g_out,
    int N, ResT rt)
{
    __shared__ __align__(16) float sW1[1024];      // 32 x 32
    __shared__ __align__(16) float sW2[1024];      // 32 x 32
    __shared__ __align__(16) float so[128 * 39];   // 19,968 B

    int tid = threadIdx.x;
    int pt  = tid >> 1;                    // local point 0..127
    int p   = tid & 1;                     // half: 0 -> levels 0..7, 1 -> 8..15
    int n   = blockIdx.x * 128 + pt;
    bool alive = (n < N);
    int nc = alive ? n : (N - 1);          // safe index for loads

    // ---- scalar-ish inputs FIRST (oldest in vmcnt queue) ----
    float posx = g_pos[3*nc+0], posy = g_pos[3*nc+1], posz = g_pos[3*nc+2];
    float rx0 = g_rx[0], rx1 = g_rx[1], rx2 = g_rx[2];
    float a0 = g_aabb[0], a1 = g_aabb[1], a2 = g_aabb[2];
    float a3 = g_aabb[3], a4 = g_aabb[4], a5 = g_aabb[5];
    int deg = g_deg[0];

    // ---- stage W1/W2 into LDS (cooperative, coalesced) ----
#pragma unroll
    for (int j = 0; j < 4; ++j) sW1[tid + 256*j] = g_W1[tid + 256*j];
#pragma unroll
    for (int j = 0; j < 4; ++j) sW2[tid + 256*j] = g_W2[tid + 256*j];

    size_t LN = (size_t)NLV * N;
    const v2f* f2 = (const v2f*)ws;
    const v4f* p4 = (const v4f*)(ws + 2*LN);
    const v2f* p2 = (const v2f*)(ws + 6*LN);

    // ---- batch-issue this half's 8 f2 pairs ----
    v2f f8[8];
#pragma unroll
    for (int j = 0; j < 8; ++j)
        f8[j] = f2[(size_t)(p * 8 + j) * N + nc];

    float s0, s1, s2, pnx, pny, pnz; bool sel;
    aabb_norm_v(a0, a1, a2, a3, a4, a5, posx, posy, posz,
                s0, s1, s2, pnx, pny, pnz, sel);
    (void)pnx; (void)pny; (void)pnz;

    __syncthreads();   // sW1/sW2 ready

    // ---- z1: exchange halves via shfl, EXACT reference level order ----
    float z1[32];
#pragma unroll
    for (int i = 0; i < 32; ++i) z1[i] = 0.f;
    float hi0[8], hi1[8];
#pragma unroll
    for (int j = 0; j < 8; ++j) {
        float t0 = __shfl_xor(f8[j].x, 1, 64);
        float t1 = __shfl_xor(f8[j].y, 1, 64);
        float lo0 = p ? t0 : f8[j].x;
        float lo1 = p ? t1 : f8[j].y;
        hi0[j] = p ? f8[j].x : t0;
        hi1[j] = p ? f8[j].y : t1;
        const float* w1a = sW1 + (2*j) * 32;
        const float* w1b = sW1 + (2*j+1) * 32;
#pragma unroll
        for (int i = 0; i < 32; ++i) {
            float acc = fmaf(lo0, w1a[i], z1[i]);   // k=2j then k=2j+1
            z1[i] = fmaf(lo1, w1b[i], acc);
        }
    }
#pragma unroll
    for (int j = 0; j < 8; ++j) {
        const float* w1a = sW1 + (2*(8+j)) * 32;
        const float* w1b = sW1 + (2*(8+j)+1) * 32;
#pragma unroll
        for (int i = 0; i < 32; ++i) {
            float acc = fmaf(hi0[j], w1a[i], z1[i]);
            z1[i] = fmaf(hi1[j], w1b[i], acc);
        }
    }

    // ---- batch-issue this half's 8 p4 + 8 p2 partials; the sh loop
    //      (1024 fmaf) below covers their latency ----
    v4f pp4[8];
    v2f pp2[8];
#pragma unroll
    for (int j = 0; j < 8; ++j) {
        pp4[j] = p4[(size_t)(p * 8 + j) * N + nc];
        pp2[j] = p2[(size_t)(p * 8 + j) * N + nc];
    }

    // ---- relu + second layer (sgemm FMA chain, ascending j) ----
    unsigned mask = 0u;
    float sh[32];
#pragma unroll
    for (int o = 0; o < 32; ++o) sh[o] = 0.f;
#pragma unroll
    for (int i = 0; i < 32; ++i) {
        bool on = (z1[i] > 0.f);
        if (on) mask |= (1u << i);
        float h = on ? z1[i] : 0.f;
        const float* w2r = sW2 + i * 32;
#pragma unroll
        for (int o = 0; o < 32; ++o) sh[o] = fmaf(h, w2r[o], sh[o]);
    }

    const float C0c = 0.28209479177387814f;
    float d0 = C0c * sh[0], d1 = C0c * sh[1];

    // ---- view dirs + SH basis + scat ----
    float dxw = rx0 - posx, dyw = rx1 - posy, dzw = rx2 - posz;
    float dnorm = sqrtf(dxw*dxw + dyw*dyw + dzw*dzw);
    float dinv = 1.f / fmaxf(dnorm, 1e-20f);
    float X = dxw * dinv, Yd = dyw * dinv, Z = dzw * dinv;
    float xx = X*X, yy = Yd*Yd, zz = Z*Z;
    float xy = X*Yd, yz = Yd*Z, xz = X*Z;
    float Yb[16];
    Yb[0]  = 0.28209479177387814f;
    Yb[1]  = -0.4886025119029199f * Yd;
    Yb[2]  =  0.4886025119029199f * Z;
    Yb[3]  = -0.4886025119029199f * X;
    Yb[4]  =  1.0925484305920792f * xy;
    Yb[5]  = -1.0925484305920792f * yz;
    Yb[6]  =  0.31539156525252005f * (2.f*zz - xx - yy);
    Yb[7]  = -1.0925484305920792f * xz;
    Yb[8]  =  0.5462742152960396f * (xx - yy);
    Yb[9]  = -0.5900435899266435f * Yd * (3.f*xx - yy);
    Yb[10] =  2.890611442640554f  * xy * Z;
    Yb[11] = -0.4570457994644658f * Yd * (4.f*zz - xx - yy);
    Yb[12] =  0.3731763325901154f * Z * (2.f*zz - 3.f*xx - 3.f*yy);
    Yb[13] = -0.4570457994644658f * X * (4.f*zz - xx - yy);
    Yb[14] =  1.445305721320277f  * Z * (xx - yy);
    Yb[15] = -0.5900435899266435f * X * (xx - 3.f*yy);

    int nact = (deg + 1) * (deg + 1);
    float sc0 = 0.f, sc1 = 0.f;
#pragma unroll
    for (int c = 0; c < 16; ++c) {
        float yc = (c < nact) ? Yb[c] : 0.f;
        sc0 = fmaf(yc, sh[2*c+0], sc0);
        sc1 = fmaf(yc, sh[2*c+1], sc1);
    }

    // ---- backward head: q = C0*d/|d| ----
    float ss = d0*d0 + d1*d1;
    float q0 = 0.f, q1 = 0.f;
    if (ss > 0.f) {
        float sr = sqrtf(ss);
        q0 = C0c * d0 / sr;
        q1 = C0c * d1 / sr;
    }
    float dzv[32];
#pragma unroll
    for (int i = 0; i < 32; ++i) {
        float dh = fmaf(q0, sW2[i*32+0], q1 * sW2[i*32+1]);
        dzv[i] = ((mask >> i) & 1u) ? dh : 0.f;
    }

    // ---- gradient: this half's 8 levels, then shfl-combine ----
    float gx = 0.f, gy = 0.f, gz = 0.f;
    const float4* w1v = (const float4*)sW1;    // row r = w1v[r*8 .. r*8+7]
    int rbase = p * 16;                        // W1 row base (2 rows/level)
#pragma unroll
    for (int j = 0; j < 8; ++j) {
        const float4* wa = w1v + (size_t)(rbase + 2*j) * 8;
        const float4* wb = wa + 8;
        float da = 0.f, db = 0.f;
#pragma unroll
        for (int k = 0; k < 8; ++k) {
            float4 va = wa[k], vb = wb[k];
            da = fmaf(va.x, dzv[4*k+0], da);
            da = fmaf(va.y, dzv[4*k+1], da);
            da = fmaf(va.z, dzv[4*k+2], da);
            da = fmaf(va.w, dzv[4*k+3], da);
            db = fmaf(vb.x, dzv[4*k+0], db);
            db = fmaf(vb.y, dzv[4*k+1], db);
            db = fmaf(vb.z, dzv[4*k+2], db);
            db = fmaf(vb.w, dzv[4*k+3], db);
        }
        float res = p ? rt.r[8+j] : rt.r[j];   // ternary: compile-time indices
        gx = fmaf(res, fmaf(da, pp4[j].x, db * pp4[j].y), gx);
        gy = fmaf(res, fmaf(da, pp4[j].z, db * pp4[j].w), gy);
        gz = fmaf(res, fmaf(da, pp2[j].x, db * pp2[j].y), gz);
    }
    float tx = __shfl_xor(gx, 1, 64);
    float ty = __shfl_xor(gy, 1, 64);
    float tz = __shfl_xor(gz, 1, 64);
    gx = gx + tx; gy = gy + ty; gz = gz + tz;   // p==0: lo+hi (ngp_fused order)

    // ---- world-space normal ----
    float gwx = gx / s0, gwy = gy / s1, gwz = gz / s2;
    float gn = sqrtf(gwx*gwx + gwy*gwy + gwz*gwz);
    float ginv = -1.f / fmaxf(gn, 1e-20f);
    float nr0 = gwx * ginv, nr1 = gwy * ginv, nr2 = gwz * ginv;

    // ---- coalesced output via LDS staging (128 points, one phase) ----
    if (p == 0 && alive) {
        float* row = so + (size_t)pt * 39;     // stride 39 dw: odd, conflict-free
        row[0] = sel ? d0  : 0.f;
        row[1] = sel ? d1  : 0.f;
        row[2] = sel ? sc0 : 0.f;
        row[3] = sel ? sc1 : 0.f;
        row[4] = sel ? nr0 : 0.f;
        row[5] = sel ? nr1 : 0.f;
        row[6] = sel ? nr2 : 0.f;
#pragma unroll
        for (int c = 0; c < 32; ++c) row[7 + c] = sel ? sh[c] : 0.f;
    }
    __syncthreads();
    int base_n = blockIdx.x * 128;
    int cnt = N - base_n; if (cnt > 128) cnt = 128;
    if (cnt > 0) {
        int nf = cnt * 39;
        int nv = nf >> 2;
        float4* dst = (float4*)(g_out + (size_t)base_n * 39);
        const float4* src = (const float4*)so;
        for (int i = tid; i < nv; i += 256) dst[i] = src[i];
        int tail = nf & 3;
        if (tid < tail)
            ((float*)dst)[(nv << 2) + tid] = ((const float*)src)[(nv << 2) + tid];
    }
}

// =====================================================================
// FALLBACK (round-7 fused kernel) if ws_size is too small.
// =====================================================================
__global__ __launch_bounds__(256, 2) void ngp_fused(
    const float* __restrict__ g_pos,
    const float* __restrict__ g_rx,
    const float* __restrict__ g_tab,
    const float* __restrict__ g_W1,
    const float* __restrict__ g_W2,
    const float* __restrict__ g_aabb,
    const int*   __restrict__ g_deg,
    float* __restrict__ g_out,
    int N, ResT rt)
{
    __shared__ float sm[48][256];

    int tid = blockIdx.x * 256 + threadIdx.x;
    int lt  = threadIdx.x;
    int n = tid >> 1;
    int p = tid & 1;
    if (n >= N) return;

    float posx = g_pos[3*n+0], posy = g_pos[3*n+1], posz = g_pos[3*n+2];
    float s0, s1, s2, pnx, pny, pnz; bool sel;
    aabb_norm(g_aabb, posx, posy, posz, s0, s1, s2, pnx, pny, pnz, sel);

    const float2* tab = (const float2*)g_tab;
    float f0o[8], f1o[8];
#pragma unroll
    for (int j = 0; j < 8; ++j) {
        float res = p ? rt.r[8+j] : rt.r[j];
        const float2* tl = tab + (size_t)(p * 8 + j) * TSZ;
        float fx = pnx * res, fy = pny * res, fz = pnz * res;
        float x0 = floorf(fx), y0 = floorf(fy), z0 = floorf(fz);
        float wx = fx - x0, wy = fy - y0, wz = fz - z0;
        float omx = 1.f - wx, omy = 1.f - wy, omz = 1.f - wz;
        unsigned ux = (unsigned)x0, uy = (unsigned)y0, uz = (unsigned)z0;
        unsigned hx0 = ux,        hx1 = ux + 1u;
        unsigned hy0 = uy * PR1,  hy1 = (uy + 1u) * PR1;
        unsigned hz0 = uz * PR2,  hz1 = (uz + 1u) * PR2;
        float f0 = 0.f, f1 = 0.f;
        float lxa = 0.f, lxb = 0.f, lya = 0.f, lyb = 0.f, lza = 0.f, lzb = 0.f;
#pragma unroll
        for (int c = 0; c < 8; ++c) {
            unsigned hh = ((c & 4) ? hx1 : hx0) ^ ((c & 2) ? hy1 : hy0) ^ ((c & 1) ? hz1 : hz0);
            float2 fv = tl[hh & TMASK];
            float wxv = (c & 4) ? wx : omx;
            float wyv = (c & 2) ? wy : omy;
            float wzv = (c & 1) ? wz : omz;
            float wgt = wxv * wyv;
            wgt = wgt * wzv;
            float t0 = fv.x * wgt;
            float t1 = fv.y * wgt;
            f0 = f0 + t0;
            f1 = f1 + t1;
            float pyz = wyv * wzv;
            float pxz = wxv * wzv;
            float pxy = wxv * wyv;
            float spx = (c & 4) ? pyz : -pyz;
            float spy = (c & 2) ? pxz : -pxz;
            float spz = (c & 1) ? pxy : -pxy;
            lxa = lxa + fv.x * spx;  lxb = lxb + fv.y * spx;
            lya = lya + fv.x * spy;  lyb = lyb + fv.y * spy;
            lza = lza + fv.x * spz;  lzb = lzb + fv.y * spz;
        }
        f0o[j] = f0; f1o[j] = f1;
        sm[j*6+0][lt] = lxa;  sm[j*6+1][lt] = lxb;
        sm[j*6+2][lt] = lya;  sm[j*6+3][lt] = lyb;
        sm[j*6+4][lt] = lza;  sm[j*6+5][lt] = lzb;
    }

    float z1[32];
#pragma unroll
    for (int i = 0; i < 32; ++i) z1[i] = 0.f;
    float hi0[8], hi1[8];
#pragma unroll
    for (int j = 0; j < 8; ++j) {
        float t0 = __shfl_xor(f0o[j], 1, 64);
        float t1 = __shfl_xor(f1o[j], 1, 64);
        float lo0 = p ? t0 : f0o[j];
        float lo1 = p ? t1 : f1o[j];
        hi0[j] = p ? f0o[j] : t0;
        hi1[j] = p ? f1o[j] : t1;
        const float* w1a = g_W1 + (2*j) * 32;
        const float* w1b = g_W1 + (2*j+1) * 32;
#pragma unroll
        for (int i = 0; i < 32; ++i) {
            float acc = fmaf(lo0, w1a[i], z1[i]);
            z1[i] = fmaf(lo1, w1b[i], acc);
        }
    }
#pragma unroll
    for (int j = 0; j < 8; ++j) {
        const float* w1a = g_W1 + (2*(8+j)) * 32;
        const float* w1b = g_W1 + (2*(8+j)+1) * 32;
#pragma unroll
        for (int i = 0; i < 32; ++i) {
            float acc = fmaf(hi0[j], w1a[i], z1[i]);
            z1[i] = fmaf(hi1[j], w1b[i], acc);
        }
    }

    unsigned mask = 0u;
    float sh[32];
#pragma unroll
    for (int o = 0; o < 32; ++o) sh[o] = 0.f;
#pragma unroll
    for (int i = 0; i < 32; ++i) {
        bool on = (z1[i] > 0.f);
        if (on) mask |= (1u << i);
        float h = on ? z1[i] : 0.f;
        const float* w2r = g_W2 + i * 32;
#pragma unroll
        for (int o = 0; o < 32; ++o) sh[o] = fmaf(h, w2r[o], sh[o]);
    }

    const float C0c = 0.28209479177387814f;
    float d0 = C0c * sh[0], d1 = C0c * sh[1];

    float rx0 = g_rx[0], rx1 = g_rx[1], rx2 = g_rx[2];
    float dxw = rx0 - posx, dyw = rx1 - posy, dzw = rx2 - posz;
    float dnorm = sqrtf(dxw*dxw + dyw*dyw + dzw*dzw);
    float dinv = 1.f / fmaxf(dnorm, 1e-20f);
    float X = dxw * dinv, Yd = dyw * dinv, Z = dzw * dinv;
    float xx = X*X, yy = Yd*Yd, zz = Z*Z;
    float xy = X*Yd, yz = Yd*Z, xz = X*Z;
    float Yb[16];
    Yb[0]  = 0.28209479177387814f;
    Yb[1]  = -0.4886025119029199f * Yd;
    Yb[2]  =  0.4886025119029199f * Z;
    Yb[3]  = -0.4886025119029199f * X;
    Yb[4]  =  1.0925484305920792f * xy;
    Yb[5]  = -1.0925484305920792f * yz;
    Yb[6]  =  0.31539156525252005f * (2.f*zz - xx - yy);
    Yb[7]  = -1.0925484305920792f * xz;
    Yb[8]  =  0.5462742152960396f * (xx - yy);
    Yb[9]  = -0.5900435899266435f * Yd * (3.f*xx - yy);
    Yb[10] =  2.890611442640554f  * xy * Z;
    Yb[11] = -0.4570457994644658f * Yd * (4.f*zz - xx - yy);
    Yb[12] =  0.3731763325901154f * Z * (2.f*zz - 3.f*xx - 3.f*yy);
    Yb[13] = -0.4570457994644658f * X * (4.f*zz - xx - yy);
    Yb[14] =  1.445305721320277f  * Z * (xx - yy);
    Yb[15] = -0.5900435899266435f * X * (xx - 3.f*yy);

    int deg = g_deg[0];
    int nact = (deg + 1) * (deg + 1);
    float sc0 = 0.f, sc1 = 0.f;
#pragma unroll
    for (int c = 0; c < 16; ++c) {
        float yc = (c < nact) ? Yb[c] : 0.f;
        sc0 = fmaf(yc, sh[2*c+0], sc0);
        sc1 = fmaf(yc, sh[2*c+1], sc1);
    }

    float* op = g_out + (size_t)n * 39;
    if (p == 0) {
        op[0] = sel ? d0  : 0.f;
        op[1] = sel ? d1  : 0.f;
        op[2] = sel ? sc0 : 0.f;
        op[3] = sel ? sc1 : 0.f;
#pragma unroll
        for (int c = 0; c < 13; ++c) op[7 + c] = sel ? sh[c] : 0.f;
    } else {
#pragma unroll
        for (int c = 13; c < 32; ++c) op[7 + c] = sel ? sh[c] : 0.f;
    }

    float ss = d0*d0 + d1*d1;
    float q0 = 0.f, q1 = 0.f;
    if (ss > 0.f) {
        float sr = sqrtf(ss);
        q0 = C0c * d0 / sr;
        q1 = C0c * d1 / sr;
    }
    float dzv[32];
#pragma unroll
    for (int i = 0; i < 32; ++i) {
        float dh = fmaf(q0, g_W2[i*32+0], q1 * g_W2[i*32+1]);
        dzv[i] = ((mask >> i) & 1u) ? dh : 0.f;
    }

    float gx = 0.f, gy = 0.f, gz = 0.f;
    const float4* w1v = (const float4*)g_W1;
    int rbase = p * 16;
#pragma unroll
    for (int j = 0; j < 8; ++j) {
        const float4* wa = w1v + (size_t)(rbase + 2*j) * 8;
        const float4* wb = wa + 8;
        float da = 0.f, db = 0.f;
#pragma unroll
        for (int k = 0; k < 8; ++k) {
            float4 va = wa[k], vb = wb[k];
            da = fmaf(va.x, dzv[4*k+0], da);
            da = fmaf(va.y, dzv[4*k+1], da);
            da = fmaf(va.z, dzv[4*k+2], da);
            da = fmaf(va.w, dzv[4*k+3], da);
            db = fmaf(vb.x, dzv[4*k+0], db);
            db = fmaf(vb.y, dzv[4*k+1], db);
            db = fmaf(vb.z, dzv[4*k+2], db);
            db = fmaf(vb.w, dzv[4*k+3], db);
        }
        float xa = sm[j*6+0][lt], xb = sm[j*6+1][lt];
        float ya = sm[j*6+2][lt], yb = sm[j*6+3][lt];
        float za = sm[j*6+4][lt], zb = sm[j*6+5][lt];
        float res = p ? rt.r[8+j] : rt.r[j];
        gx = fmaf(res, fmaf(da, xa, db * xb), gx);
        gy = fmaf(res, fmaf(da, ya, db * yb), gy);
        gz = fmaf(res, fmaf(da, za, db * zb), gz);
    }
    float tx = __shfl_xor(gx, 1, 64);
    float ty = __shfl_xor(gy, 1, 64);
    float tz = __shfl_xor(gz, 1, 64);
    gx = gx + tx; gy = gy + ty; gz = gz + tz;

    float gwx = gx / s0, gwy = gy / s1, gwz = gz / s2;
    float gn = sqrtf(gwx*gwx + gwy*gwy + gwz*gwz);
    float ginv = -1.f / fmaxf(gn, 1e-20f);
    if (p == 0) {
        op[4] = sel ? gwx * ginv : 0.f;
        op[5] = sel ? gwy * ginv : 0.f;
        op[6] = sel ? gwz * ginv : 0.f;
    }
}

extern "C" void kernel_launch(void* const* d_in, const int* in_sizes, int n_in,
                              void* d_out, int out_size, void* d_ws, size_t ws_size,
                              hipStream_t stream)
{
    const float* g_pos  = (const float*)d_in[0];
    const float* g_rx   = (const float*)d_in[1];
    const float* g_tab  = (const float*)d_in[2];
    const float* g_W1   = (const float*)d_in[3];
    const float* g_W2   = (const float*)d_in[4];
    const float* g_aabb = (const float*)d_in[5];
    const int*   g_deg  = (const int*)d_in[6];
    float* g_out = (float*)d_out;

    int N = in_sizes[0] / 3;

    // RES exactly as the reference: python float64 exp/log/pow, cast to fp32.
    ResT rt;
    double scale = exp((log(4096.0) - log(16.0)) / 15.0);
    for (int l = 0; l < NLV; ++l) rt.r[l] = (float)(16.0 * pow(scale, (double)l));

    size_t need = (size_t)NLV * N * 8 * sizeof(float);   // 134 MB at N=262144
    if (ws_size >= need) {
        float* ws = (float*)d_ws;
        int chunks = (N + 255) / 256;
        level_gather<<<NLV * chunks, 256, 0, stream>>>(g_pos, g_tab, g_aabb,
                                                       ws, N, chunks, rt);
        int chunks_b = (N + 127) / 128;
        mlp_bwd<<<chunks_b, 256, 0, stream>>>(g_pos, g_rx, g_W1, g_W2, g_aabb,
                                              g_deg, ws, g_out, N, rt);
    } else {
        long long threads = 2LL * N;
        int blocks = (int)((threads + 255) / 256);
        ngp_fused<<<blocks, 256, 0, stream>>>(g_pos, g_rx, g_tab, g_W1, g_W2,
                                              g_aabb, g_deg, g_out, N, rt);
    }
}

// Round 9
// 334.611 us; speedup vs baseline: 2.9932x; 2.9932x over previous
//
#include <hip/hip_runtime.h>
#include <cmath>

// Forbid FMA contraction: the reference check is a float32 numpy replay with
// individually-rounded ops. We opt into FMA explicitly (fmaf) only where
// BLAS sgemm itself uses an FMA chain.
#pragma clang fp contract(off)

#define NLV 16
#define TSZ (1u << 19)
#define TMASK (TSZ - 1u)
#define PR1 2654435761u
#define PR2 805459861u

typedef float v2f __attribute__((ext_vector_type(2)));
typedef float v4f __attribute__((ext_vector_type(4)));

struct ResT { float r[NLV]; };

// ---------- shared helpers (bit-exact fp32, matches np reference) ----------
__device__ __forceinline__ void aabb_norm(
    const float* __restrict__ g_aabb, float posx, float posy, float posz,
    float& s0, float& s1, float& s2,
    float& pnx, float& pny, float& pnz, bool& sel)
{
    float a0 = g_aabb[0], a1 = g_aabb[1], a2 = g_aabb[2];
    s0 = fmaxf(g_aabb[3] - a0, 1e-6f);
    s1 = fmaxf(g_aabb[4] - a1, 1e-6f);
    s2 = fmaxf(g_aabb[5] - a2, 1e-6f);
    float nx = (posx - a0) / s0;
    float ny = (posy - a1) / s1;
    float nz = (posz - a2) / s2;
    sel = (nx >= 0.f) && (nx <= 1.f) && (ny >= 0.f) && (ny <= 1.f)
       && (nz >= 0.f) && (nz <= 1.f);
    pnx = fminf(fmaxf(nx, 0.f), 1.f);
    pny = fminf(fmaxf(ny, 0.f), 1.f);
    pnz = fminf(fmaxf(nz, 0.f), 1.f);
}

// =====================================================================
// PASS A: one (point, level) per thread. MEASURED-BEST CONFIG (167-172
// us, FETCH 95 MB): two time phases; phase 0 runs levels 0..7 with
// level l pinned to XCD l (b%8 round-robin), phase 1 runs levels 8..15.
// Each XCD holds ONE 4 MB table slice at a time -> L2-resident. Floor =
// L2 random-request throughput (~10 req/cyc/XCD), request count is
// mapping-invariant -> structural floor for this pass.
// NT stores are load-bearing (r7: plain stores stream 16 MB of dirty ws
// per XCD through the 4 MB L2 holding the pinned slice -> pass A 260us).
// ws layout packed for pass B:
//   f2[l*N+n]  = (f0,f1)           (v2f plane)
//   p4[l*N+n]  = (xa,xb,ya,yb)     (v4f plane)
//   p2[l*N+n]  = (za,zb)           (v2f plane)
// =====================================================================
__global__ __launch_bounds__(256) void level_gather(
    const float* __restrict__ g_pos,
    const float* __restrict__ g_tab,
    const float* __restrict__ g_aabb,
    float* __restrict__ ws,
    int N, int chunks, ResT rt)
{
    int b = blockIdx.x;
    int half = (b >= 8 * chunks) ? 1 : 0;
    int bb = b - half * (8 * chunks);
    int lvl = (bb & 7) + (half << 3);
    int n = (bb >> 3) * 256 + threadIdx.x;
    if (n >= N) return;

    float posx = g_pos[3*n+0], posy = g_pos[3*n+1], posz = g_pos[3*n+2];
    float s0, s1, s2, pnx, pny, pnz; bool sel;
    aabb_norm(g_aabb, posx, posy, posz, s0, s1, s2, pnx, pny, pnz, sel);

    float res = rt.r[lvl];                       // wave-uniform scalar
    const float2* tl = (const float2*)g_tab + (size_t)lvl * TSZ;

    float fx = pnx * res, fy = pny * res, fz = pnz * res;
    float x0 = floorf(fx), y0 = floorf(fy), z0 = floorf(fz);
    float wx = fx - x0, wy = fy - y0, wz = fz - z0;
    float omx = 1.f - wx, omy = 1.f - wy, omz = 1.f - wz;
    unsigned ux = (unsigned)x0, uy = (unsigned)y0, uz = (unsigned)z0;
    unsigned hx0 = ux,        hx1 = ux + 1u;
    unsigned hy0 = uy * PR1,  hy1 = (uy + 1u) * PR1;
    unsigned hz0 = uz * PR2,  hz1 = (uz + 1u) * PR2;
    float f0 = 0.f, f1 = 0.f;
    float lxa = 0.f, lxb = 0.f, lya = 0.f, lyb = 0.f, lza = 0.f, lzb = 0.f;
#pragma unroll
    for (int c = 0; c < 8; ++c) {
        unsigned hh = ((c & 4) ? hx1 : hx0) ^ ((c & 2) ? hy1 : hy0) ^ ((c & 1) ? hz1 : hz0);
        float2 fv = tl[hh & TMASK];
        float wxv = (c & 4) ? wx : omx;
        float wyv = (c & 2) ? wy : omy;
        float wzv = (c & 1) ? wz : omz;
        // forward: wc = (x*y)*z, each op rounded; f += fv*wc seq c=0..7
        float wgt = wxv * wyv;
        wgt = wgt * wzv;
        float t0 = fv.x * wgt;
        float t1 = fv.y * wgt;
        f0 = f0 + t0;
        f1 = f1 + t1;
        // gradient partials (sign flip by corner bit is exact)
        float pyz = wyv * wzv;
        float pxz = wxv * wzv;
        float pxy = wxv * wyv;
        float spx = (c & 4) ? pyz : -pyz;
        float spy = (c & 2) ? pxz : -pxz;
        float spz = (c & 1) ? pxy : -pxy;
        lxa = lxa + fv.x * spx;  lxb = lxb + fv.y * spx;
        lya = lya + fv.x * spy;  lyb = lyb + fv.y * spy;
        lza = lza + fv.x * spz;  lzb = lzb + fv.y * spz;
    }

    size_t LN = (size_t)NLV * N;
    size_t idx = (size_t)lvl * N + n;
    v2f* f2 = (v2f*)ws;                  // 2*LN floats
    v4f* p4 = (v4f*)(ws + 2*LN);         // 4*LN floats
    v2f* p2 = (v2f*)(ws + 6*LN);         // 2*LN floats
    v2f ff = {f0, f1};
    v4f pa = {lxa, lxb, lya, lyb};
    v2f pz = {lza, lzb};
    __builtin_nontemporal_store(ff, f2 + idx);
    __builtin_nontemporal_store(pa, p4 + idx);
    __builtin_nontemporal_store(pz, p2 + idx);
}

// =====================================================================
// PASS B: one thread per point. Combination of the two fastest measured
// variants:
//  - compute structure of the 327-us round (early seeds + rolling-4
//    prefetch on f2 and p4/p2; weights from global — L1/SMEM-cached);
//  - store placement of the 151-us round: op[0..3] and op[7..38] written
//    RIGHT AFTER scat, so sh[32]'s live range ENDS before the grad
//    section. Peak VGPR stays under the 128 occupancy cliff (waves/SIMD
//    halve at >128) — this occupancy, not load depth, is pass B's lever
//    (r5-r8: every deep-ILP attempt spilled at 256 VGPR).
// No LDS, no launch_bounds cap (r7: cap-forced spill).
// FP order identical to validated kernels -> absmax unchanged.
// =====================================================================
__global__ __launch_bounds__(256) void mlp_bwd(
    const float* __restrict__ g_pos,
    const float* __restrict__ g_rx,
    const float* __restrict__ g_W1,
    const float* __restrict__ g_W2,
    const float* __restrict__ g_aabb,
    const int*   __restrict__ g_deg,
    const float* __restrict__ ws,
    float* __restrict__ g_out,
    int N, ResT rt)
{
    int n = blockIdx.x * 256 + threadIdx.x;
    if (n >= N) return;

    size_t LN = (size_t)NLV * N;
    const v2f* f2 = (const v2f*)ws;
    const v4f* p4 = (const v4f*)(ws + 2*LN);
    const v2f* p2 = (const v2f*)(ws + 6*LN);

    // ---- issue early loads: first 4 f2 and first 4 p4/p2 ----
    v2f fv[4];
#pragma unroll
    for (int j = 0; j < 4; ++j) fv[j] = f2[(size_t)j * N + n];
    v4f pc4[4];
    v2f pc2[4];
#pragma unroll
    for (int j = 0; j < 4; ++j) {
        pc4[j] = p4[(size_t)j * N + n];
        pc2[j] = p2[(size_t)j * N + n];
    }

    float posx = g_pos[3*n+0], posy = g_pos[3*n+1], posz = g_pos[3*n+2];
    float s0, s1, s2, pnx, pny, pnz; bool sel;
    aabb_norm(g_aabb, posx, posy, posz, s0, s1, s2, pnx, pny, pnz, sel);
    (void)pnx; (void)pny; (void)pnz;

    // ---- z1 = feats@W1, exact level order, sgemm FMA chain ascending k ----
    float z1[32];
#pragma unroll
    for (int i = 0; i < 32; ++i) z1[i] = 0.f;
#pragma unroll
    for (int l = 0; l < NLV; ++l) {
        v2f fvl = fv[l & 3];
        if (l + 4 < NLV) fv[l & 3] = f2[(size_t)(l + 4) * N + n];  // 4 ahead
        float f0 = fvl.x;
        float f1 = fvl.y;
        const float* w1a = g_W1 + (2*l) * 32;
        const float* w1b = g_W1 + (2*l+1) * 32;
#pragma unroll
        for (int i = 0; i < 32; ++i) {
            float acc = fmaf(f0, w1a[i], z1[i]);   // k=2l then k=2l+1
            z1[i] = fmaf(f1, w1b[i], acc);
        }
    }

    // ---- relu + second layer (sgemm FMA chain, ascending j) ----
    unsigned mask = 0u;
    float sh[32];
#pragma unroll
    for (int o = 0; o < 32; ++o) sh[o] = 0.f;
#pragma unroll
    for (int i = 0; i < 32; ++i) {
        bool on = (z1[i] > 0.f);
        if (on) mask |= (1u << i);
        float h = on ? z1[i] : 0.f;
        const float* w2r = g_W2 + i * 32;
#pragma unroll
        for (int o = 0; o < 32; ++o) sh[o] = fmaf(h, w2r[o], sh[o]);
    }

    const float C0c = 0.28209479177387814f;
    float d0 = C0c * sh[0], d1 = C0c * sh[1];

    // ---- view dirs + SH basis + scat ----
    float rx0 = g_rx[0], rx1 = g_rx[1], rx2 = g_rx[2];
    float dxw = rx0 - posx, dyw = rx1 - posy, dzw = rx2 - posz;
    float dnorm = sqrtf(dxw*dxw + dyw*dyw + dzw*dzw);
    float dinv = 1.f / fmaxf(dnorm, 1e-20f);
    float X = dxw * dinv, Yd = dyw * dinv, Z = dzw * dinv;
    float xx = X*X, yy = Yd*Yd, zz = Z*Z;
    float xy = X*Yd, yz = Yd*Z, xz = X*Z;
    float Yb[16];
    Yb[0]  = 0.28209479177387814f;
    Yb[1]  = -0.4886025119029199f * Yd;
    Yb[2]  =  0.4886025119029199f * Z;
    Yb[3]  = -0.4886025119029199f * X;
    Yb[4]  =  1.0925484305920792f * xy;
    Yb[5]  = -1.0925484305920792f * yz;
    Yb[6]  =  0.31539156525252005f * (2.f*zz - xx - yy);
    Yb[7]  = -1.0925484305920792f * xz;
    Yb[8]  =  0.5462742152960396f * (xx - yy);
    Yb[9]  = -0.5900435899266435f * Yd * (3.f*xx - yy);
    Yb[10] =  2.890611442640554f  * xy * Z;
    Yb[11] = -0.4570457994644658f * Yd * (4.f*zz - xx - yy);
    Yb[12] =  0.3731763325901154f * Z * (2.f*zz - 3.f*xx - 3.f*yy);
    Yb[13] = -0.4570457994644658f * X * (4.f*zz - xx - yy);
    Yb[14] =  1.445305721320277f  * Z * (xx - yy);
    Yb[15] = -0.5900435899266435f * X * (xx - 3.f*yy);

    int deg = g_deg[0];
    int nact = (deg + 1) * (deg + 1);
    float sc0 = 0.f, sc1 = 0.f;
#pragma unroll
    for (int c = 0; c < 16; ++c) {
        float yc = (c < nact) ? Yb[c] : 0.f;
        sc0 = fmaf(yc, sh[2*c+0], sc0);
        sc1 = fmaf(yc, sh[2*c+1], sc1);
    }

    // ---- EARLY stores: sh's live range ends HERE (before grad) ----
    float* op = g_out + (size_t)n * 39;
    op[0] = sel ? d0  : 0.f;
    op[1] = sel ? d1  : 0.f;
    op[2] = sel ? sc0 : 0.f;
    op[3] = sel ? sc1 : 0.f;
#pragma unroll
    for (int c = 0; c < 32; ++c) op[7 + c] = sel ? sh[c] : 0.f;

    // ---- backward head: q = C0*d/|d| ----
    float ss = d0*d0 + d1*d1;
    float q0 = 0.f, q1 = 0.f;
    if (ss > 0.f) {
        float sr = sqrtf(ss);
        q0 = C0c * d0 / sr;
        q1 = C0c * d1 / sr;
    }
    float dzv[32];
#pragma unroll
    for (int i = 0; i < 32; ++i) {
        float dh = fmaf(q0, g_W2[i*32+0], q1 * g_W2[i*32+1]);
        dzv[i] = ((mask >> i) & 1u) ? dh : 0.f;
    }

    // ---- gradient: per level, da/db from W1 (L1-hit) x partials from ws ----
    // pc4/pc2[0..3] issued at kernel entry; keep 4 levels ahead.
    float gx = 0.f, gy = 0.f, gz = 0.f;
    const float4* w1v = (const float4*)g_W1;   // row r = w1v[r*8 .. r*8+7]
#pragma unroll
    for (int l = 0; l < NLV; ++l) {
        v4f c4 = pc4[l & 3];
        v2f c2 = pc2[l & 3];
        if (l + 4 < NLV) {
            pc4[l & 3] = p4[(size_t)(l + 4) * N + n];   // 4 ahead
            pc2[l & 3] = p2[(size_t)(l + 4) * N + n];
        }
        const float4* wa = w1v + (size_t)(2*l) * 8;
        const float4* wb = wa + 8;
        float da = 0.f, db = 0.f;
#pragma unroll
        for (int k = 0; k < 8; ++k) {
            float4 va = wa[k], vb = wb[k];
            da = fmaf(va.x, dzv[4*k+0], da);
            da = fmaf(va.y, dzv[4*k+1], da);
            da = fmaf(va.z, dzv[4*k+2], da);
            da = fmaf(va.w, dzv[4*k+3], da);
            db = fmaf(vb.x, dzv[4*k+0], db);
            db = fmaf(vb.y, dzv[4*k+1], db);
            db = fmaf(vb.z, dzv[4*k+2], db);
            db = fmaf(vb.w, dzv[4*k+3], db);
        }
        float res = rt.r[l];
        gx = fmaf(res, fmaf(da, c4.x, db * c4.y), gx);
        gy = fmaf(res, fmaf(da, c4.z, db * c4.w), gy);
        gz = fmaf(res, fmaf(da, c2.x, db * c2.y), gz);
    }

    // ---- world-space normal ----
    float gwx = gx / s0, gwy = gy / s1, gwz = gz / s2;
    float gn = sqrtf(gwx*gwx + gwy*gwy + gwz*gwz);
    float ginv = -1.f / fmaxf(gn, 1e-20f);
    op[4] = sel ? gwx * ginv : 0.f;
    op[5] = sel ? gwy * ginv : 0.f;
    op[6] = sel ? gwz * ginv : 0.f;
}

// =====================================================================
// FALLBACK (round-7 fused kernel) if ws_size is too small.
// =====================================================================
__global__ __launch_bounds__(256, 2) void ngp_fused(
    const float* __restrict__ g_pos,
    const float* __restrict__ g_rx,
    const float* __restrict__ g_tab,
    const float* __restrict__ g_W1,
    const float* __restrict__ g_W2,
    const float* __restrict__ g_aabb,
    const int*   __restrict__ g_deg,
    float* __restrict__ g_out,
    int N, ResT rt)
{
    __shared__ float sm[48][256];

    int tid = blockIdx.x * 256 + threadIdx.x;
    int lt  = threadIdx.x;
    int n = tid >> 1;
    int p = tid & 1;
    if (n >= N) return;

    float posx = g_pos[3*n+0], posy = g_pos[3*n+1], posz = g_pos[3*n+2];
    float s0, s1, s2, pnx, pny, pnz; bool sel;
    aabb_norm(g_aabb, posx, posy, posz, s0, s1, s2, pnx, pny, pnz, sel);

    const float2* tab = (const float2*)g_tab;
    float f0o[8], f1o[8];
#pragma unroll
    for (int j = 0; j < 8; ++j) {
        float res = p ? rt.r[8+j] : rt.r[j];
        const float2* tl = tab + (size_t)(p * 8 + j) * TSZ;
        float fx = pnx * res, fy = pny * res, fz = pnz * res;
        float x0 = floorf(fx), y0 = floorf(fy), z0 = floorf(fz);
        float wx = fx - x0, wy = fy - y0, wz = fz - z0;
        float omx = 1.f - wx, omy = 1.f - wy, omz = 1.f - wz;
        unsigned ux = (unsigned)x0, uy = (unsigned)y0, uz = (unsigned)z0;
        unsigned hx0 = ux,        hx1 = ux + 1u;
        unsigned hy0 = uy * PR1,  hy1 = (uy + 1u) * PR1;
        unsigned hz0 = uz * PR2,  hz1 = (uz + 1u) * PR2;
        float f0 = 0.f, f1 = 0.f;
        float lxa = 0.f, lxb = 0.f, lya = 0.f, lyb = 0.f, lza = 0.f, lzb = 0.f;
#pragma unroll
        for (int c = 0; c < 8; ++c) {
            unsigned hh = ((c & 4) ? hx1 : hx0) ^ ((c & 2) ? hy1 : hy0) ^ ((c & 1) ? hz1 : hz0);
            float2 fv = tl[hh & TMASK];
            float wxv = (c & 4) ? wx : omx;
            float wyv = (c & 2) ? wy : omy;
            float wzv = (c & 1) ? wz : omz;
            float wgt = wxv * wyv;
            wgt = wgt * wzv;
            float t0 = fv.x * wgt;
            float t1 = fv.y * wgt;
            f0 = f0 + t0;
            f1 = f1 + t1;
            float pyz = wyv * wzv;
            float pxz = wxv * wzv;
            float pxy = wxv * wyv;
            float spx = (c & 4) ? pyz : -pyz;
            float spy = (c & 2) ? pxz : -pxz;
            float spz = (c & 1) ? pxy : -pxy;
            lxa = lxa + fv.x * spx;  lxb = lxb + fv.y * spx;
            lya = lya + fv.x * spy;  lyb = lyb + fv.y * spy;
            lza = lza + fv.x * spz;  lzb = lzb + fv.y * spz;
        }
        f0o[j] = f0; f1o[j] = f1;
        sm[j*6+0][lt] = lxa;  sm[j*6+1][lt] = lxb;
        sm[j*6+2][lt] = lya;  sm[j*6+3][lt] = lyb;
        sm[j*6+4][lt] = lza;  sm[j*6+5][lt] = lzb;
    }

    float z1[32];
#pragma unroll
    for (int i = 0; i < 32; ++i) z1[i] = 0.f;
    float hi0[8], hi1[8];
#pragma unroll
    for (int j = 0; j < 8; ++j) {
        float t0 = __shfl_xor(f0o[j], 1, 64);
        float t1 = __shfl_xor(f1o[j], 1, 64);
        float lo0 = p ? t0 : f0o[j];
        float lo1 = p ? t1 : f1o[j];
        hi0[j] = p ? f0o[j] : t0;
        hi1[j] = p ? f1o[j] : t1;
        const float* w1a = g_W1 + (2*j) * 32;
        const float* w1b = g_W1 + (2*j+1) * 32;
#pragma unroll
        for (int i = 0; i < 32; ++i) {
            float acc = fmaf(lo0, w1a[i], z1[i]);
            z1[i] = fmaf(lo1, w1b[i], acc);
        }
    }
#pragma unroll
    for (int j = 0; j < 8; ++j) {
        const float* w1a = g_W1 + (2*(8+j)) * 32;
        const float* w1b = g_W1 + (2*(8+j)+1) * 32;
#pragma unroll
        for (int i = 0; i < 32; ++i) {
            float acc = fmaf(hi0[j], w1a[i], z1[i]);
            z1[i] = fmaf(hi1[j], w1b[i], acc);
        }
    }

    unsigned mask = 0u;
    float sh[32];
#pragma unroll
    for (int o = 0; o < 32; ++o) sh[o] = 0.f;
#pragma unroll
    for (int i = 0; i < 32; ++i) {
        bool on = (z1[i] > 0.f);
        if (on) mask |= (1u << i);
        float h = on ? z1[i] : 0.f;
        const float* w2r = g_W2 + i * 32;
#pragma unroll
        for (int o = 0; o < 32; ++o) sh[o] = fmaf(h, w2r[o], sh[o]);
    }

    const float C0c = 0.28209479177387814f;
    float d0 = C0c * sh[0], d1 = C0c * sh[1];

    float rx0 = g_rx[0], rx1 = g_rx[1], rx2 = g_rx[2];
    float dxw = rx0 - posx, dyw = rx1 - posy, dzw = rx2 - posz;
    float dnorm = sqrtf(dxw*dxw + dyw*dyw + dzw*dzw);
    float dinv = 1.f / fmaxf(dnorm, 1e-20f);
    float X = dxw * dinv, Yd = dyw * dinv, Z = dzw * dinv;
    float xx = X*X, yy = Yd*Yd, zz = Z*Z;
    float xy = X*Yd, yz = Yd*Z, xz = X*Z;
    float Yb[16];
    Yb[0]  = 0.28209479177387814f;
    Yb[1]  = -0.4886025119029199f * Yd;
    Yb[2]  =  0.4886025119029199f * Z;
    Yb[3]  = -0.4886025119029199f * X;
    Yb[4]  =  1.0925484305920792f * xy;
    Yb[5]  = -1.0925484305920792f * yz;
    Yb[6]  =  0.31539156525252005f * (2.f*zz - xx - yy);
    Yb[7]  = -1.0925484305920792f * xz;
    Yb[8]  =  0.5462742152960396f * (xx - yy);
    Yb[9]  = -0.5900435899266435f * Yd * (3.f*xx - yy);
    Yb[10] =  2.890611442640554f  * xy * Z;
    Yb[11] = -0.4570457994644658f * Yd * (4.f*zz - xx - yy);
    Yb[12] =  0.3731763325901154f * Z * (2.f*zz - 3.f*xx - 3.f*yy);
    Yb[13] = -0.4570457994644658f * X * (4.f*zz - xx - yy);
    Yb[14] =  1.445305721320277f  * Z * (xx - yy);
    Yb[15] = -0.5900435899266435f * X * (xx - 3.f*yy);

    int deg = g_deg[0];
    int nact = (deg + 1) * (deg + 1);
    float sc0 = 0.f, sc1 = 0.f;
#pragma unroll
    for (int c = 0; c < 16; ++c) {
        float yc = (c < nact) ? Yb[c] : 0.f;
        sc0 = fmaf(yc, sh[2*c+0], sc0);
        sc1 = fmaf(yc, sh[2*c+1], sc1);
    }

    float* op = g_out + (size_t)n * 39;
    if (p == 0) {
        op[0] = sel ? d0  : 0.f;
        op[1] = sel ? d1  : 0.f;
        op[2] = sel ? sc0 : 0.f;
        op[3] = sel ? sc1 : 0.f;
#pragma unroll
        for (int c = 0; c < 13; ++c) op[7 + c] = sel ? sh[c] : 0.f;
    } else {
#pragma unroll
        for (int c = 13; c < 32; ++c) op[7 + c] = sel ? sh[c] : 0.f;
    }

    float ss = d0*d0 + d1*d1;
    float q0 = 0.f, q1 = 0.f;
    if (ss > 0.f) {
        float sr = sqrtf(ss);
        q0 = C0c * d0 / sr;
        q1 = C0c * d1 / sr;
    }
    float dzv[32];
#pragma unroll
    for (int i = 0; i < 32; ++i) {
        float dh = fmaf(q0, g_W2[i*32+0], q1 * g_W2[i*32+1]);
        dzv[i] = ((mask >> i) & 1u) ? dh : 0.f;
    }

    float gx = 0.f, gy = 0.f, gz = 0.f;
    const float4* w1v = (const float4*)g_W1;
    int rbase = p * 16;
#pragma unroll
    for (int j = 0; j < 8; ++j) {
        const float4* wa = w1v + (size_t)(rbase + 2*j) * 8;
        const float4* wb = wa + 8;
        float da = 0.f, db = 0.f;
#pragma unroll
        for (int k = 0; k < 8; ++k) {
            float4 va = wa[k], vb = wb[k];
            da = fmaf(va.x, dzv[4*k+0], da);
            da = fmaf(va.y, dzv[4*k+1], da);
            da = fmaf(va.z, dzv[4*k+2], da);
            da = fmaf(va.w, dzv[4*k+3], da);
            db = fmaf(vb.x, dzv[4*k+0], db);
            db = fmaf(vb.y, dzv[4*k+1], db);
            db = fmaf(vb.z, dzv[4*k+2], db);
            db = fmaf(vb.w, dzv[4*k+3], db);
        }
        float xa = sm[j*6+0][lt], xb = sm[j*6+1][lt];
        float ya = sm[j*6+2][lt], yb = sm[j*6+3][lt];
        float za = sm[j*6+4][lt], zb = sm[j*6+5][lt];
        float res = p ? rt.r[8+j] : rt.r[j];
        gx = fmaf(res, fmaf(da, xa, db * xb), gx);
        gy = fmaf(res, fmaf(da, ya, db * yb), gy);
        gz = fmaf(res, fmaf(da, za, db * zb), gz);
    }
    float tx = __shfl_xor(gx, 1, 64);
    float ty = __shfl_xor(gy, 1, 64);
    float tz = __shfl_xor(gz, 1, 64);
    gx = gx + tx; gy = gy + ty; gz = gz + tz;

    float gwx = gx / s0, gwy = gy / s1, gwz = gz / s2;
    float gn = sqrtf(gwx*gwx + gwy*gwy + gwz*gwz);
    float ginv = -1.f / fmaxf(gn, 1e-20f);
    if (p == 0) {
        op[4] = sel ? gwx * ginv : 0.f;
        op[5] = sel ? gwy * ginv : 0.f;
        op[6] = sel ? gwz * ginv : 0.f;
    }
}

extern "C" void kernel_launch(void* const* d_in, const int* in_sizes, int n_in,
                              void* d_out, int out_size, void* d_ws, size_t ws_size,
                              hipStream_t stream)
{
    const float* g_pos  = (const float*)d_in[0];
    const float* g_rx   = (const float*)d_in[1];
    const float* g_tab  = (const float*)d_in[2];
    const float* g_W1   = (const float*)d_in[3];
    const float* g_W2   = (const float*)d_in[4];
    const float* g_aabb = (const float*)d_in[5];
    const int*   g_deg  = (const int*)d_in[6];
    float* g_out = (float*)d_out;

    int N = in_sizes[0] / 3;

    // RES exactly as the reference: python float64 exp/log/pow, cast to fp32.
    ResT rt;
    double scale = exp((log(4096.0) - log(16.0)) / 15.0);
    for (int l = 0; l < NLV; ++l) rt.r[l] = (float)(16.0 * pow(scale, (double)l));

    size_t need = (size_t)NLV * N * 8 * sizeof(float);   // 134 MB at N=262144
    if (ws_size >= need) {
        float* ws = (float*)d_ws;
        int chunks = (N + 255) / 256;
        level_gather<<<NLV * chunks, 256, 0, stream>>>(g_pos, g_tab, g_aabb,
                                                       ws, N, chunks, rt);
        mlp_bwd<<<chunks, 256, 0, stream>>>(g_pos, g_rx, g_W1, g_W2, g_aabb,
                                            g_deg, ws, g_out, N, rt);
    } else {
        long long threads = 2LL * N;
        int blocks = (int)((threads + 255) / 256);
        ngp_fused<<<blocks, 256, 0, stream>>>(g_pos, g_rx, g_tab, g_W1, g_W2,
                                              g_aabb, g_deg, g_out, N, rt);
    }
}